// Round 1
// baseline (511.232 us; speedup 1.0000x reference)
//
#include <hip/hip_runtime.h>

// Problem constants (from reference): NGH=7, SUBQ=8, SUBD=1, POS_D=3, NEG_D=5,
// BORDER=16, SUBD_NEG=8.  B=4, C=128, H=W=256.
#define CCH   128
#define HH    256
#define WW    256
#define BB    4
#define H1    28
#define W1    28
#define QTOT  3136           // BB*H1*W1
#define NPOS  29
#define NNEG  80
#define NDIS  3136           // same grid as queries (SUBD_NEG == SUBQ)
#define SCOLS 3217           // 1 + NNEG + NDIS

// Offsets enumerated exactly in reference order (j outer ascending, i inner).
__constant__ int POS_I[NPOS] = {
  0,
  -2,-1,0,1,2,
  -2,-1,0,1,2,
  -3,-2,-1,0,1,2,3,
  -2,-1,0,1,2,
  -2,-1,0,1,2,
  0};
__constant__ int POS_J[NPOS] = {
  -3,
  -2,-2,-2,-2,-2,
  -1,-1,-1,-1,-1,
  0,0,0,0,0,0,0,
  1,1,1,1,1,
  2,2,2,2,2,
  3};

__constant__ int NEG_I[NNEG] = {
  0,                                  // j=-7
  -3,-2,-1,0,1,2,3,                   // j=-6
  -4,-3,-2,-1,0,1,2,3,4,              // j=-5
  -5,-4,-3,3,4,5,                     // j=-4
  -6,-5,-4,4,5,6,                     // j=-3
  -6,-5,5,6,                          // j=-2
  -6,-5,5,6,                          // j=-1
  -7,-6,-5,5,6,7,                     // j=0
  -6,-5,5,6,                          // j=1
  -6,-5,5,6,                          // j=2
  -6,-5,-4,4,5,6,                     // j=3
  -5,-4,-3,3,4,5,                     // j=4
  -4,-3,-2,-1,0,1,2,3,4,              // j=5
  -3,-2,-1,0,1,2,3,                   // j=6
  0};                                 // j=7
__constant__ int NEG_J[NNEG] = {
  -7,
  -6,-6,-6,-6,-6,-6,-6,
  -5,-5,-5,-5,-5,-5,-5,-5,-5,
  -4,-4,-4,-4,-4,-4,
  -3,-3,-3,-3,-3,-3,
  -2,-2,-2,-2,
  -1,-1,-1,-1,
  0,0,0,0,0,0,
  1,1,1,1,
  2,2,2,2,
  3,3,3,3,3,3,
  4,4,4,4,4,4,
  5,5,5,5,5,5,5,5,5,
  6,6,6,6,6,6,6,
  7};

// ---------------- Kernel A: gather F1 / F2g, compute xy2 + mask ----------------
__global__ void gather_kernel(const float* __restrict__ feat1,
                              const float* __restrict__ feat2,
                              const float* __restrict__ aflow,
                              float* __restrict__ F1, float* __restrict__ F2g,
                              int* __restrict__ X2, int* __restrict__ Y2,
                              float* __restrict__ mask_out) {
  int q = blockIdx.x;
  int c = threadIdx.x;
  int b = q / (H1 * W1);
  int r = q % (H1 * W1);
  int y = 16 + 8 * (r / W1);
  int x = 16 + 8 * (r % W1);
  size_t base = ((size_t)(b * CCH) * HH + y) * WW + x;
  F1 [(size_t)q * CCH + c] = feat1[base + (size_t)c * HH * WW];
  F2g[(size_t)q * CCH + c] = feat2[base + (size_t)c * HH * WW];
  if (c == 0) {
    float ax = aflow[((size_t)(b * 2 + 0) * HH + y) * WW + x];
    float ay = aflow[((size_t)(b * 2 + 1) * HH + y) * WW + x];
    int x2 = (int)(ax + 0.5f);   // matches (aflow+0.5).astype(int32)
    int y2 = (int)(ay + 0.5f);
    X2[q] = x2;
    Y2[q] = y2;
    mask_out[q] = (x2 >= 0 && y2 >= 0 && x2 < WW && y2 < HH) ? 1.0f : 0.0f;
  }
}

// ------------- Kernel B: pos/neg scores, argmax, qconf, gt[0..80] --------------
__global__ void posneg_kernel(const float* __restrict__ feat2,
                              const float* __restrict__ conf1,
                              const float* __restrict__ conf2,
                              const float* __restrict__ F1,
                              const int* __restrict__ X2, const int* __restrict__ Y2,
                              float* __restrict__ scores, float* __restrict__ gt,
                              float* __restrict__ qconf_out) {
  __shared__ float f1s[CCH];
  __shared__ float ps[NPOS];
  int q = blockIdx.x;
  int t = threadIdx.x;
  int b = q / (H1 * W1);
  int r = q % (H1 * W1);
  int y = 16 + 8 * (r / W1);
  int x = 16 + 8 * (r % W1);
  f1s[t] = F1[(size_t)q * CCH + t];
  int x2 = X2[q], y2 = Y2[q];
  __syncthreads();

  if (t < NPOS + NNEG) {
    int di, dj;
    if (t < NPOS) { di = POS_I[t];        dj = POS_J[t]; }
    else          { di = NEG_I[t - NPOS]; dj = NEG_J[t - NPOS]; }
    int xk = min(max(x2 + di, 0), WW - 1);
    int yk = min(max(y2 + dj, 0), HH - 1);
    const float* p = feat2 + ((size_t)(b * CCH) * HH + yk) * WW + xk;
    float acc = 0.f;
    #pragma unroll 8
    for (int cc = 0; cc < CCH; ++cc)
      acc += f1s[cc] * p[(size_t)cc * HH * WW];
    if (t < NPOS) ps[t] = acc;
    else          scores[(size_t)q * SCOLS + 1 + (t - NPOS)] = acc;
  }
  if (t < 1 + NNEG)
    gt[(size_t)q * SCOLS + t] = (t == 0) ? 1.0f : 0.0f;
  __syncthreads();

  if (t == 0) {
    float best = ps[0];
    int bi = 0;
    for (int k = 1; k < NPOS; ++k)
      if (ps[k] > best) { best = ps[k]; bi = k; }   // first-occurrence argmax
    scores[(size_t)q * SCOLS] = best;
    int sx = min(max(x2 + POS_I[bi], 0), WW - 1);
    int sy = min(max(y2 + POS_J[bi], 0), HH - 1);
    float c1 = conf1[((size_t)b * HH + y) * WW + x];
    float c2 = conf2[((size_t)b * HH + sy) * WW + sx];
    qconf_out[q] = 0.5f * (c1 + c2);
  }
}

// --------- Kernel C: distractor GEMM (Q x ND, K=128) + dist mask + gt ----------
#define TS 16
__global__ void dscore_kernel(const float* __restrict__ F1,
                              const float* __restrict__ F2g,
                              const int* __restrict__ X2, const int* __restrict__ Y2,
                              float* __restrict__ scores, float* __restrict__ gt) {
  __shared__ float As[TS][CCH + 1];   // +1 pad: kills same-bank stride-128 reads
  __shared__ float Bs[TS][CCH + 1];
  int tx = threadIdx.x, ty = threadIdx.y;
  int tid = ty * TS + tx;
  int qbase = blockIdx.y * TS;
  int dbase = blockIdx.x * TS;

  #pragma unroll
  for (int it = 0; it < (TS * CCH) / (TS * TS); ++it) {   // 8 iters
    int idx = tid + it * TS * TS;
    int row = idx >> 7;              // /128
    int col = idx & (CCH - 1);       // %128
    As[row][col] = F1 [(size_t)(qbase + row) * CCH + col];
    Bs[row][col] = F2g[(size_t)(dbase + row) * CCH + col];
  }
  __syncthreads();

  float acc = 0.f;
  #pragma unroll 8
  for (int kk = 0; kk < CCH; ++kk)
    acc += As[ty][kk] * Bs[tx][kk];

  int q = qbase + ty, d = dbase + tx;
  int db = d / (H1 * W1);
  int dr = d % (H1 * W1);
  int dy = 16 + 8 * (dr / W1);
  int dx = 16 + 8 * (dr % W1);
  int x2 = X2[q], y2 = Y2[q];
  int qb = q / (H1 * W1);
  int ddx = dx - x2, ddy = dy - y2;
  int dis2 = ddx * ddx + ddy * ddy + (db != qb ? 25 : 0);   // NEG_D^2 = 25
  if (dis2 < 25) acc = 0.f;

  size_t o = (size_t)q * SCOLS + 1 + NNEG + d;
  scores[o] = acc;
  gt[o] = 0.f;
}

extern "C" void kernel_launch(void* const* d_in, const int* in_sizes, int n_in,
                              void* d_out, int out_size, void* d_ws, size_t ws_size,
                              hipStream_t stream) {
  const float* feat1 = (const float*)d_in[0];
  const float* feat2 = (const float*)d_in[1];
  const float* conf1 = (const float*)d_in[2];
  const float* conf2 = (const float*)d_in[3];
  const float* aflow = (const float*)d_in[4];

  float* out       = (float*)d_out;
  float* scores    = out;                                   // Q x SCOLS
  float* gt        = out + (size_t)QTOT * SCOLS;            // Q x SCOLS
  float* mask_out  = out + 2 * (size_t)QTOT * SCOLS;        // Q
  float* qconf_out = mask_out + QTOT;                       // Q

  float* F1  = (float*)d_ws;                                // Q x C
  float* F2g = F1 + (size_t)QTOT * CCH;                     // Q x C
  int*   X2  = (int*)(F2g + (size_t)QTOT * CCH);
  int*   Y2  = X2 + QTOT;

  gather_kernel<<<QTOT, CCH, 0, stream>>>(feat1, feat2, aflow, F1, F2g, X2, Y2, mask_out);
  posneg_kernel<<<QTOT, 128, 0, stream>>>(feat2, conf1, conf2, F1, X2, Y2, scores, gt, qconf_out);
  dim3 gridC(NDIS / TS, QTOT / TS);
  dim3 blockC(TS, TS);
  dscore_kernel<<<gridC, blockC, 0, stream>>>(F1, F2g, X2, Y2, scores, gt);
}

// Round 2
// 343.958 us; speedup vs baseline: 1.4863x; 1.4863x over previous
//
#include <hip/hip_runtime.h>

// NGH=7, SUBQ=8, SUBD=1, POS_D=3, NEG_D=5, BORDER=16, SUBD_NEG=8. B=4,C=128,H=W=256.
#define CCH   128
#define HH    256
#define WW    256
#define BB    4
#define H1    28
#define W1    28
#define QTOT  3136
#define NPOS  29
#define NNEG  80
#define NDIS  3136
#define SCOLS 3217          // 1 + NNEG + NDIS

typedef short s8v __attribute__((ext_vector_type(8)));   // 8 bf16 (4 VGPRs)
typedef float f4v __attribute__((ext_vector_type(4)));   // MFMA accumulator

__device__ __forceinline__ unsigned short f2bf(float f) {  // RNE fp32->bf16
  unsigned int u = __float_as_uint(f);
  u += 0x7fffu + ((u >> 16) & 1u);
  return (unsigned short)(u >> 16);
}
__device__ __forceinline__ float bf2f(unsigned short h) {
  return __uint_as_float(((unsigned int)h) << 16);
}

// Offsets in exact reference enumeration order (j outer asc, i inner asc).
__constant__ int POS_I[NPOS] = {
  0, -2,-1,0,1,2, -2,-1,0,1,2, -3,-2,-1,0,1,2,3, -2,-1,0,1,2, -2,-1,0,1,2, 0};
__constant__ int POS_J[NPOS] = {
  -3, -2,-2,-2,-2,-2, -1,-1,-1,-1,-1, 0,0,0,0,0,0,0, 1,1,1,1,1, 2,2,2,2,2, 3};
__constant__ int NEG_I[NNEG] = {
  0, -3,-2,-1,0,1,2,3, -4,-3,-2,-1,0,1,2,3,4, -5,-4,-3,3,4,5, -6,-5,-4,4,5,6,
  -6,-5,5,6, -6,-5,5,6, -7,-6,-5,5,6,7, -6,-5,5,6, -6,-5,5,6, -6,-5,-4,4,5,6,
  -5,-4,-3,3,4,5, -4,-3,-2,-1,0,1,2,3,4, -3,-2,-1,0,1,2,3, 0};
__constant__ int NEG_J[NNEG] = {
  -7, -6,-6,-6,-6,-6,-6,-6, -5,-5,-5,-5,-5,-5,-5,-5,-5, -4,-4,-4,-4,-4,-4,
  -3,-3,-3,-3,-3,-3, -2,-2,-2,-2, -1,-1,-1,-1, 0,0,0,0,0,0, 1,1,1,1, 2,2,2,2,
  3,3,3,3,3,3, 4,4,4,4,4,4, 5,5,5,5,5,5,5,5,5, 6,6,6,6,6,6,6, 7};

// ---- Kernel T: feat2 (B,C,H,W) fp32 -> feat2T (B,H,W,C) bf16 ----
__global__ void transpose_kernel(const float* __restrict__ feat2,
                                 unsigned short* __restrict__ feat2T) {
  __shared__ unsigned short tile[CCH][33];   // odd-ish stride: <=2-way conflicts (free)
  int x0 = blockIdx.x * 32;
  int y  = blockIdx.y;
  int b  = blockIdx.z;
  int tid = threadIdx.x;
  const float* src = feat2 + ((size_t)b * CCH * HH + y) * WW;   // + c*H*W + x
  #pragma unroll
  for (int it = 0; it < 16; ++it) {
    int idx = it * 256 + tid;
    int c = idx >> 5, xi = idx & 31;
    tile[c][xi] = f2bf(src[(size_t)c * HH * WW + x0 + xi]);  // lanes across x: coalesced
  }
  __syncthreads();
  int xi = tid >> 3, cg = (tid & 7) * 16;
  __align__(16) unsigned short tmp[16];
  #pragma unroll
  for (int k = 0; k < 16; ++k) tmp[k] = tile[cg + k][xi];
  unsigned short* dst = feat2T + ((size_t)((b * HH + y) * WW) + x0 + xi) * CCH + cg;
  *(uint4*)dst       = *(const uint4*)tmp;       // 8 KB fully-contiguous block write
  *(uint4*)(dst + 8) = *(const uint4*)(tmp + 8);
}

// ---- Kernel A: gather F1bf (strided NCHW), F2bf (coalesced NHWC), xy2, mask ----
__global__ void gather_kernel(const float* __restrict__ feat1,
                              const unsigned short* __restrict__ feat2T,
                              const float* __restrict__ aflow,
                              unsigned short* __restrict__ F1bf,
                              unsigned short* __restrict__ F2bf,
                              int* __restrict__ X2, int* __restrict__ Y2,
                              float* __restrict__ mask_out) {
  int q = blockIdx.x, c = threadIdx.x;
  int b = q / (H1 * W1), r = q % (H1 * W1);
  int y = 16 + 8 * (r / W1);
  int x = 16 + 8 * (r % W1);
  F1bf[(size_t)q * CCH + c] = f2bf(feat1[((size_t)(b * CCH + c) * HH + y) * WW + x]);
  F2bf[(size_t)q * CCH + c] = feat2T[((size_t)((b * HH + y) * WW) + x) * CCH + c];
  if (c == 0) {
    float ax = aflow[((size_t)(b * 2 + 0) * HH + y) * WW + x];
    float ay = aflow[((size_t)(b * 2 + 1) * HH + y) * WW + x];
    int x2 = (int)(ax + 0.5f);
    int y2 = (int)(ay + 0.5f);
    X2[q] = x2; Y2[q] = y2;
    mask_out[q] = (x2 >= 0 && y2 >= 0 && x2 < WW && y2 < HH) ? 1.0f : 0.0f;
  }
}

// ---- Kernel B: pos/neg scores (contiguous NHWC reads), argmax, qconf, gt head ----
__global__ void posneg_kernel(const unsigned short* __restrict__ feat2T,
                              const float* __restrict__ conf1,
                              const float* __restrict__ conf2,
                              const unsigned short* __restrict__ F1bf,
                              const int* __restrict__ X2, const int* __restrict__ Y2,
                              float* __restrict__ scores, float* __restrict__ gt,
                              float* __restrict__ qconf_out) {
  __shared__ float f1s[CCH];
  __shared__ float ps[NPOS];
  int q = blockIdx.x, t = threadIdx.x;
  int b = q / (H1 * W1), r = q % (H1 * W1);
  int y = 16 + 8 * (r / W1);
  int x = 16 + 8 * (r % W1);
  if (t < CCH) f1s[t] = bf2f(F1bf[(size_t)q * CCH + t]);
  int x2 = X2[q], y2 = Y2[q];
  __syncthreads();

  if (t < 2 * (NPOS + NNEG)) {             // 218 threads: 2 per offset
    int off = t >> 1, half = t & 1;
    int di = (off < NPOS) ? POS_I[off] : NEG_I[off - NPOS];
    int dj = (off < NPOS) ? POS_J[off] : NEG_J[off - NPOS];
    int xk = min(max(x2 + di, 0), WW - 1);
    int yk = min(max(y2 + dj, 0), HH - 1);
    const uint4* p4 = (const uint4*)(feat2T +
        ((size_t)((b * HH + yk) * WW) + xk) * CCH + half * 64);
    float acc = 0.f;
    #pragma unroll
    for (int i = 0; i < 8; ++i) {          // 8 x 16B = 64 bf16 contiguous
      uint4 v = p4[i];
      const unsigned int vs[4] = {v.x, v.y, v.z, v.w};
      #pragma unroll
      for (int j = 0; j < 4; ++j) {
        int c = half * 64 + i * 8 + j * 2;
        acc += f1s[c]     * __uint_as_float(vs[j] << 16);
        acc += f1s[c + 1] * __uint_as_float(vs[j] & 0xffff0000u);
      }
    }
    acc += __shfl_xor(acc, 1);             // combine halves (same wave)
    if (half == 0) {
      if (off < NPOS) ps[off] = acc;
      else            scores[(size_t)q * SCOLS + 1 + (off - NPOS)] = acc;
    }
  }
  if (t < 1 + NNEG)
    gt[(size_t)q * SCOLS + t] = (t == 0) ? 1.0f : 0.0f;
  __syncthreads();

  if (t == 0) {
    float best = ps[0]; int bi = 0;
    for (int k = 1; k < NPOS; ++k)
      if (ps[k] > best) { best = ps[k]; bi = k; }   // first-occurrence argmax
    scores[(size_t)q * SCOLS] = best;
    int sx = min(max(x2 + POS_I[bi], 0), WW - 1);
    int sy = min(max(y2 + POS_J[bi], 0), HH - 1);
    float c1 = conf1[((size_t)b * HH + y) * WW + x];
    float c2 = conf2[((size_t)b * HH + sy) * WW + sx];
    qconf_out[q] = 0.5f * (c1 + c2);
  }
}

// ---- Kernel C: distractor scores via bf16 MFMA + distance mask + gt tail ----
// Wave computes 16q x 64d; block (4 waves) = 64q x 64d. K=128 -> 4 MFMA steps.
__global__ void dscore_kernel(const unsigned short* __restrict__ F1bf,
                              const unsigned short* __restrict__ F2bf,
                              const int* __restrict__ X2, const int* __restrict__ Y2,
                              float* __restrict__ scores, float* __restrict__ gt) {
  int w = threadIdx.x >> 6, lane = threadIdx.x & 63;
  int qb = blockIdx.y * 64 + w * 16;
  int db = blockIdx.x * 64;
  int m  = lane & 15;            // A row / B col within tile
  int ko = (lane >> 4) * 8;      // k-offset of this lane's 8 elements

  f4v acc[4];
  #pragma unroll
  for (int dt = 0; dt < 4; ++dt) acc[dt] = (f4v){0.f, 0.f, 0.f, 0.f};

  #pragma unroll
  for (int kk = 0; kk < 4; ++kk) {
    s8v a = *(const s8v*)(F1bf + (size_t)(qb + m) * CCH + kk * 32 + ko);
    #pragma unroll
    for (int dt = 0; dt < 4; ++dt) {
      s8v bfr = *(const s8v*)(F2bf + (size_t)(db + dt * 16 + m) * CCH + kk * 32 + ko);
      acc[dt] = __builtin_amdgcn_mfma_f32_16x16x32_bf16(a, bfr, acc[dt], 0, 0, 0);
    }
  }

  // C/D layout: col = lane&15, row = (lane>>4)*4 + reg  [verified m89/m91]
  int rbase = (lane >> 4) * 4, col = lane & 15;
  int x2v[4], y2v[4], qbat[4];
  #pragma unroll
  for (int r = 0; r < 4; ++r) {
    int q = qb + rbase + r;
    x2v[r] = X2[q]; y2v[r] = Y2[q]; qbat[r] = q / (H1 * W1);
  }
  #pragma unroll
  for (int dt = 0; dt < 4; ++dt) {
    int d = db + dt * 16 + col;
    int dbat = d / (H1 * W1), dr = d % (H1 * W1);
    int dy = 16 + 8 * (dr / W1), dx = 16 + 8 * (dr % W1);
    #pragma unroll
    for (int r = 0; r < 4; ++r) {
      int q = qb + rbase + r;
      int ddx = dx - x2v[r], ddy = dy - y2v[r];
      int dis2 = ddx * ddx + ddy * ddy + (dbat != qbat[r] ? 25 : 0);
      float v = acc[dt][r];
      if (dis2 < 25) v = 0.f;
      size_t o = (size_t)q * SCOLS + 1 + NNEG + d;
      scores[o] = v;
      gt[o] = 0.f;
    }
  }
}

extern "C" void kernel_launch(void* const* d_in, const int* in_sizes, int n_in,
                              void* d_out, int out_size, void* d_ws, size_t ws_size,
                              hipStream_t stream) {
  const float* feat1 = (const float*)d_in[0];
  const float* feat2 = (const float*)d_in[1];
  const float* conf1 = (const float*)d_in[2];
  const float* conf2 = (const float*)d_in[3];
  const float* aflow = (const float*)d_in[4];

  float* out       = (float*)d_out;
  float* scores    = out;
  float* gt        = out + (size_t)QTOT * SCOLS;
  float* mask_out  = out + 2 * (size_t)QTOT * SCOLS;
  float* qconf_out = mask_out + QTOT;

  unsigned short* feat2T = (unsigned short*)d_ws;                 // B*H*W*C bf16 = 67 MB
  unsigned short* F1bf   = feat2T + (size_t)BB * HH * WW * CCH;   // Q*C
  unsigned short* F2bf   = F1bf + (size_t)QTOT * CCH;             // Q*C
  int* X2 = (int*)(F2bf + (size_t)QTOT * CCH);
  int* Y2 = X2 + QTOT;

  dim3 gT(WW / 32, HH, BB);
  transpose_kernel<<<gT, 256, 0, stream>>>(feat2, feat2T);
  gather_kernel<<<QTOT, CCH, 0, stream>>>(feat1, feat2T, aflow, F1bf, F2bf, X2, Y2, mask_out);
  posneg_kernel<<<QTOT, 256, 0, stream>>>(feat2T, conf1, conf2, F1bf, X2, Y2, scores, gt, qconf_out);
  dim3 gD(NDIS / 64, QTOT / 64);
  dscore_kernel<<<gD, 256, 0, stream>>>(F1bf, F2bf, X2, Y2, scores, gt);
}